// Round 6
// baseline (261.897 us; speedup 1.0000x reference)
//
#include <hip/hip_runtime.h>
#include <hip/hip_cooperative_groups.h>
#include <hip/hip_bf16.h>
#include <stdint.h>

// LinearTimeSelfAttention MI355X, round 10:
//  - R5 failure diagnosed as cooperative-launch rejection (absmax == max|ref|
//    => y stayed zeroed; launch error was unchecked). This round:
//      * host queries hipOccupancyMaxActiveBlocksPerMultiprocessor; coop
//        mono kernel only if >=256 blocks co-resident; ELSE fall back to the
//        proven R4 3-kernel pipeline (guaranteed 183.5us floor).
//      * ALL cross-phase global data inside mono moved to coherent-by-
//        construction paths: P1 tail = fence-free memory-side atomicAdd
//        (R1/R4-proven); P3/P4 handoffs via relaxed agent-scope atomic
//        load/store (L2-bypassing; NO threadfence -- R3 proved fences
//        catastrophic). Read-only inputs are the only plain cross-phase data.
// Folding: y = Bm@x + cvec; Bm = A@W_q; A = (W_out ctx)/S;
// ctx = sum_n e^k v^T; S = sum_n e^k.

namespace cg = cooperative_groups;

#define NPOS 147456      // 384*384
#define NTILES 2304      // NPOS / 64
#define NB1 512          // 2 blocks/CU exactly

typedef __attribute__((ext_vector_type(8))) short short8;
typedef __attribute__((ext_vector_type(4))) float floatx4;

__device__ __forceinline__ uint16_t f2bf(float f) {
    uint32_t u = __float_as_uint(f);
    return (uint16_t)((u + 0x7fffu + ((u >> 16) & 1u)) >> 16);   // RNE
}
__device__ __forceinline__ uint32_t pack2(float a, float b) {
#if __has_builtin(__builtin_amdgcn_cvt_pk_bf16_f32)
    auto r = __builtin_amdgcn_cvt_pk_bf16_f32(a, b);
    uint32_t u; __builtin_memcpy(&u, &r, sizeof(u));
    return u;
#else
    return (uint32_t)f2bf(a) | ((uint32_t)f2bf(b) << 16);
#endif
}

// agent-scope relaxed atomics: bypass the (non-coherent) per-XCD L2s,
// coherent with memory-side atomicAdd. No fences.
__device__ __forceinline__ float aloadf(const float* p) {
    return __hip_atomic_load(p, __ATOMIC_RELAXED, __HIP_MEMORY_SCOPE_AGENT);
}
__device__ __forceinline__ void astoref(float* p, float v) {
    __hip_atomic_store(p, v, __ATOMIC_RELAXED, __HIP_MEMORY_SCOPE_AGENT);
}
__device__ __forceinline__ void astoreu(uint32_t* p, uint32_t v) {
    __hip_atomic_store(p, v, __ATOMIC_RELAXED, __HIP_MEMORY_SCOPE_AGENT);
}
__device__ __forceinline__ short8 aload_s8(const uint32_t* p) {
    union { uint64_t u[2]; short8 s; } c;
    c.u[0] = __hip_atomic_load((const uint64_t*)p,       __ATOMIC_RELAXED, __HIP_MEMORY_SCOPE_AGENT);
    c.u[1] = __hip_atomic_load((const uint64_t*)(p + 2), __ATOMIC_RELAXED, __HIP_MEMORY_SCOPE_AGENT);
    return c.s;
}

// strides in 32-bit LDS words
#define XS_STRIDE 68     // 136 bf16 per n-row (128 ch + 8 pad)
#define PS_STRIDE 36     // 72 bf16 per kvrow (64 n + 8 pad)
#define WST_STRIDE 132   // W staging: 128 f32 + 4 pad

// ---- helpers ----
__device__ __forceinline__ void k1_load(const float* __restrict__ xb, float* pf) {
    #pragma unroll
    for (int i = 0; i < 32; ++i) pf[i] = xb[(size_t)i * NPOS];
}
__device__ __forceinline__ void k1_store(uint32_t* Xsbuf, const float* pf, int lane, int c0) {
    #pragma unroll
    for (int i = 0; i < 8; ++i) {
        uint2 w;
        w.x = pack2(pf[i * 4 + 0], pf[i * 4 + 1]);
        w.y = pack2(pf[i * 4 + 2], pf[i * 4 + 3]);
        *(uint2*)&Xsbuf[lane * XS_STRIDE + (c0 + i * 4) / 2] = w;
    }
}
__device__ __forceinline__ void k1_tile(
    const uint32_t* __restrict__ Xsbuf, uint32_t* __restrict__ Psw,
    const short8 (&wfr)[4][4], const float (&biasv)[4],
    floatx4 (&acc2)[4], float (&sacc)[2], int m, int quad)
{
    #pragma unroll
    for (int nt = 0; nt < 4; ++nt) {
        short8 afr[4];
        #pragma unroll
        for (int ks = 0; ks < 4; ++ks)
            afr[ks] = *(const short8*)&Xsbuf[(nt * 16 + m) * XS_STRIDE + ks * 16 + quad * 4];
        floatx4 pa[4];
        #pragma unroll
        for (int kt = 0; kt < 4; ++kt) pa[kt] = (floatx4){0.f, 0.f, 0.f, 0.f};
        #pragma unroll
        for (int ks = 0; ks < 4; ++ks)
            #pragma unroll
            for (int kt = 0; kt < 4; ++kt)
                pa[kt] = __builtin_amdgcn_mfma_f32_16x16x32_bf16(afr[ks], wfr[kt][ks], pa[kt], 0, 0, 0);
        #pragma unroll
        for (int kt = 0; kt < 4; ++kt) {
            float v0 = pa[kt][0] + biasv[kt];
            float v1 = pa[kt][1] + biasv[kt];
            float v2 = pa[kt][2] + biasv[kt];
            float v3 = pa[kt][3] + biasv[kt];
            if (kt < 2) {   // k rows of this head
                v0 = __expf(v0); v1 = __expf(v1);
                v2 = __expf(v2); v3 = __expf(v3);
                sacc[kt] += (v0 + v1) + (v2 + v3);
            }
            uint2 w;
            w.x = pack2(v0, v1);
            w.y = pack2(v2, v3);
            *(uint2*)&Psw[(kt * 16 + m) * PS_STRIDE + nt * 8 + quad * 2] = w;
        }
    }
    #pragma unroll
    for (int ks = 0; ks < 2; ++ks) {
        short8 ea[2], vb[2];
        #pragma unroll
        for (int dt = 0; dt < 2; ++dt)
            ea[dt] = *(const short8*)&Psw[(dt * 16 + m) * PS_STRIDE + ks * 16 + quad * 4];
        #pragma unroll
        for (int et = 0; et < 2; ++et)
            vb[et] = *(const short8*)&Psw[(32 + et * 16 + m) * PS_STRIDE + ks * 16 + quad * 4];
        #pragma unroll
        for (int dt = 0; dt < 2; ++dt)
            #pragma unroll
            for (int et = 0; et < 2; ++et)
                acc2[dt * 2 + et] = __builtin_amdgcn_mfma_f32_16x16x32_bf16(ea[dt], vb[et], acc2[dt * 2 + et], 0, 0, 0);
    }
}

// ---------------- Phase 1: projections + exp + partial ctx (atomic tail) ----
__device__ __forceinline__ void phase1(
    uint32_t* smem, const float* __restrict__ x, const float* __restrict__ w_qkv,
    const float* __restrict__ b_qkv, float* __restrict__ ctxP, int nb1,
    int b, int t, int lane, int wavu, int m, int quad, int c0)
{
    uint32_t* const Xs0 = smem;
    uint32_t* const Xs1 = smem + 64 * XS_STRIDE;
    uint32_t* const Ps  = smem + 2 * 64 * XS_STRIDE;
    uint32_t* const Psw = &Ps[wavu * 64 * PS_STRIDE];

    const int T0 = NTILES / nb1, R = NTILES % nb1;
    const int cnt_tiles = T0 + (b < R ? 1 : 0);
    const int s0 = (b < R) ? b * (T0 + 1) : R * (T0 + 1) + (b - R) * T0;

    const float* xw = x + (size_t)c0 * NPOS + lane;
    float pfA[32], pfB[32];

    k1_load(xw + (size_t)s0 * 64, pfA);

    // W fragments via LDS staging, coalesced 256B reads
    short8 wfr[4][4];
    float biasv[4];
    float* const Wst = (float*)smem + wavu * (32 * WST_STRIDE);
    #pragma unroll
    for (int pass = 0; pass < 2; ++pass) {
        const int rbase = (pass == 0 ? 128 : 256) + wavu * 32;
        const float* g = w_qkv + (size_t)rbase * 128;
        #pragma unroll
        for (int i = 0; i < 64; ++i) {
            const int idx = i * 64 + lane;
            Wst[(idx >> 7) * WST_STRIDE + (idx & 127)] = g[idx];
        }
        __syncthreads();
        #pragma unroll
        for (int kt = 0; kt < 2; ++kt) {
            const int lr = kt * 16 + m;
            #pragma unroll
            for (int ks = 0; ks < 4; ++ks) {
                const float* p = &Wst[lr * WST_STRIDE + ks * 32 + quad * 8];
                float4 a = *(const float4*)p;
                float4 c = *(const float4*)(p + 4);
                short8 w;
                w[0] = (short)f2bf(a.x); w[1] = (short)f2bf(a.y);
                w[2] = (short)f2bf(a.z); w[3] = (short)f2bf(a.w);
                w[4] = (short)f2bf(c.x); w[5] = (short)f2bf(c.y);
                w[6] = (short)f2bf(c.z); w[7] = (short)f2bf(c.w);
                wfr[pass * 2 + kt][ks] = w;
            }
            biasv[pass * 2 + kt] = b_qkv[rbase + kt * 16 + m];
        }
        __syncthreads();
    }

    floatx4 acc2[4];
    #pragma unroll
    for (int i = 0; i < 4; ++i) acc2[i] = (floatx4){0.f, 0.f, 0.f, 0.f};
    float sacc[2] = {0.f, 0.f};

    if (cnt_tiles > 1) k1_load(xw + (size_t)(s0 + 1) * 64, pfB);
    k1_store(Xs0, pfA, lane, c0);
    __syncthreads();

    for (int i = 0; i < cnt_tiles; i += 2) {
        if (i + 2 < cnt_tiles) k1_load(xw + (size_t)(s0 + i + 2) * 64, pfA);
        k1_tile(Xs0, Psw, wfr, biasv, acc2, sacc, m, quad);
        if (i + 1 < cnt_tiles) k1_store(Xs1, pfB, lane, c0);
        __syncthreads();
        if (i + 1 < cnt_tiles) {
            if (i + 3 < cnt_tiles) k1_load(xw + (size_t)(s0 + i + 3) * 64, pfB);
            k1_tile(Xs1, Psw, wfr, biasv, acc2, sacc, m, quad);
            if (i + 2 < cnt_tiles) k1_store(Xs0, pfA, lane, c0);
            __syncthreads();
        }
    }

    // fence-free memory-side atomic reduce into replica (b & 7)
    float* __restrict__ dst = ctxP + (size_t)(b & 7) * 4224;
    #pragma unroll
    for (int dt = 0; dt < 2; ++dt)
        #pragma unroll
        for (int et = 0; et < 2; ++et)
            #pragma unroll
            for (int r = 0; r < 4; ++r) {
                const int d = dt * 16 + quad * 4 + r, e = et * 16 + m;
                atomicAdd(&dst[wavu * 1024 + d * 32 + e], acc2[dt * 2 + et][r]);
            }
    #pragma unroll
    for (int kt = 0; kt < 2; ++kt) {
        float s = sacc[kt];
        s += __shfl_down(s, 32, 64);
        s += __shfl_down(s, 16, 64);
        if (lane < 16) atomicAdd(&dst[4096 + wavu * 32 + kt * 16 + lane], s);
    }
}

// ---------------- Phase 3: per-o A row -> bf16 Bm row + cvec ----------------
__device__ __forceinline__ void phase3(
    uint32_t* smem, const float* __restrict__ ctxP, const float* __restrict__ w_out,
    const float* __restrict__ w_qkv, const float* __restrict__ b_qkv,
    const float* __restrict__ b_out, uint32_t* __restrict__ Bmb,
    float* __restrict__ cvec, int o, int t)
{
    float* const ctx33 = (float*)smem;          // 128*33
    float* const Ss    = ctx33 + 128 * 33;      // 128
    float* const Arow  = Ss + 128;              // 128
    float* const rowS  = Arow + 128;            // 128
    float* const red   = rowS + 128;            // 128
    for (int j = t; j < 4224; j += 256) {
        float s = 0.f;
        #pragma unroll
        for (int p = 0; p < 8; ++p) s += aloadf(&ctxP[p * 4224 + j]);
        if (j < 4096) ctx33[(j >> 5) * 33 + (j & 31)] = s;
        else          Ss[j - 4096] = s;
    }
    __syncthreads();
    if (t < 128) {   // A[o][hd], hd = t
        const int h = t >> 5;
        float s = 0.f;
        #pragma unroll
        for (int e = 0; e < 32; ++e)
            s = fmaf(w_out[o * 128 + h * 32 + e], ctx33[t * 33 + e], s);
        Arow[t] = s / Ss[t];
    }
    __syncthreads();
    if (t < 128) {   // Bm[o][c], c = t
        float s = 0.f;
        #pragma unroll 16
        for (int hd = 0; hd < 128; ++hd)
            s = fmaf(Arow[hd], w_qkv[hd * 128 + t], s);
        rowS[t] = s;
        red[t] = Arow[t] * b_qkv[t];
    }
    __syncthreads();
    if (t < 64) astoreu(&Bmb[o * 64 + t], pack2(rowS[2 * t], rowS[2 * t + 1]));
    if (t == 0) {
        float cs = b_out[o];
        #pragma unroll 8
        for (int i = 0; i < 128; ++i) cs += red[i];
        astoref(&cvec[o], cs);
    }
}

// ---------------- Phase 4: y = Bm @ x + cvec (looped tiles) -----------------
__device__ __forceinline__ void phase4(
    uint32_t* smem, const float* __restrict__ x, const uint32_t* __restrict__ Bmb,
    const float* __restrict__ cvec, float* __restrict__ y, int nb1,
    int b, int lane, int wavu, int m, int quad, int c0)
{
    uint32_t* const Xs3 = smem;
    const int T3 = NTILES / nb1, R3 = NTILES % nb1;
    const int cnt3 = T3 + (b < R3 ? 1 : 0);
    const int s03 = (b < R3) ? b * (T3 + 1) : R3 * (T3 + 1) + (b - R3) * T3;

    short8 bfr[2][4];
    float cv[2];
    #pragma unroll
    for (int ot = 0; ot < 2; ++ot) {
        const int o = (wavu * 2 + ot) * 16 + m;
        cv[ot] = aloadf(&cvec[o]);
        #pragma unroll
        for (int ks = 0; ks < 4; ++ks)
            bfr[ot][ks] = aload_s8(&Bmb[o * 64 + ks * 16 + quad * 4]);
    }

    float pf[32];
    k1_load(x + (size_t)c0 * NPOS + (size_t)s03 * 64 + lane, pf);

    for (int s = 0; s < cnt3; ++s) {
        if (s) __syncthreads();
        k1_store(Xs3, pf, lane, c0);
        __syncthreads();
        if (s + 1 < cnt3)
            k1_load(x + (size_t)c0 * NPOS + (size_t)(s03 + s + 1) * 64 + lane, pf);

        const int n0 = (s03 + s) * 64;
        floatx4 acc[2][4];
        #pragma unroll
        for (int ot = 0; ot < 2; ++ot)
            #pragma unroll
            for (int nt = 0; nt < 4; ++nt) acc[ot][nt] = (floatx4){0.f, 0.f, 0.f, 0.f};
        #pragma unroll
        for (int nt = 0; nt < 4; ++nt) {
            short8 afr[4];
            #pragma unroll
            for (int ks = 0; ks < 4; ++ks)
                afr[ks] = *(const short8*)&Xs3[(nt * 16 + m) * XS_STRIDE + ks * 16 + quad * 4];
            #pragma unroll
            for (int ks = 0; ks < 4; ++ks)
                #pragma unroll
                for (int ot = 0; ot < 2; ++ot)
                    acc[ot][nt] = __builtin_amdgcn_mfma_f32_16x16x32_bf16(afr[ks], bfr[ot][ks], acc[ot][nt], 0, 0, 0);
        }
        #pragma unroll
        for (int ot = 0; ot < 2; ++ot) {
            const int o = (wavu * 2 + ot) * 16 + m;
            #pragma unroll
            for (int nt = 0; nt < 4; ++nt) {
                floatx4 v = acc[ot][nt];
                v.x += cv[ot]; v.y += cv[ot]; v.z += cv[ot]; v.w += cv[ot];
                *(floatx4*)(y + (size_t)o * NPOS + n0 + nt * 16 + quad * 4) = v;
            }
        }
    }
}

// ---------------- kernels ----------------
__global__ __launch_bounds__(256, 2) void mono(
    const float* __restrict__ x, const float* __restrict__ w_qkv,
    const float* __restrict__ b_qkv, const float* __restrict__ w_out,
    const float* __restrict__ b_out, float* __restrict__ ctxP,
    uint32_t* __restrict__ Bmb, float* __restrict__ cvec,
    float* __restrict__ y, int nb1)
{
    __shared__ uint32_t smem[2 * 64 * XS_STRIDE + 256 * PS_STRIDE];
    const int t = threadIdx.x;
    const int lane = t & 63;
    const int wavu = __builtin_amdgcn_readfirstlane(t >> 6);
    const int m = lane & 15, quad = lane >> 4;
    const int c0 = wavu * 32;
    const int b = blockIdx.x;

    phase1(smem, x, w_qkv, b_qkv, ctxP, nb1, b, t, lane, wavu, m, quad, c0);
    cg::this_grid().sync();
    if (b < 128) phase3(smem, ctxP, w_out, w_qkv, b_qkv, b_out, Bmb, cvec, b, t);
    cg::this_grid().sync();
    phase4(smem, x, Bmb, cvec, y, nb1, b, lane, wavu, m, quad, c0);
}

__global__ __launch_bounds__(256, 2) void k1s(
    const float* __restrict__ x, const float* __restrict__ w_qkv,
    const float* __restrict__ b_qkv, float* __restrict__ ctxP, int nb1)
{
    __shared__ uint32_t smem[2 * 64 * XS_STRIDE + 256 * PS_STRIDE];
    const int t = threadIdx.x, lane = t & 63;
    const int wavu = __builtin_amdgcn_readfirstlane(t >> 6);
    phase1(smem, x, w_qkv, b_qkv, ctxP, nb1, blockIdx.x, t, lane, wavu,
           lane & 15, lane >> 4, wavu * 32);
}

__global__ __launch_bounds__(256) void k2s(
    const float* __restrict__ ctxP, const float* __restrict__ w_out,
    const float* __restrict__ w_qkv, const float* __restrict__ b_qkv,
    const float* __restrict__ b_out, uint32_t* __restrict__ Bmb,
    float* __restrict__ cvec)
{
    __shared__ uint32_t smem[4736];
    phase3(smem, ctxP, w_out, w_qkv, b_qkv, b_out, Bmb, cvec, blockIdx.x, threadIdx.x);
}

__global__ __launch_bounds__(256) void k3s(
    const float* __restrict__ x, const uint32_t* __restrict__ Bmb,
    const float* __restrict__ cvec, float* __restrict__ y, int nb1)
{
    __shared__ uint32_t smem[64 * XS_STRIDE];
    const int t = threadIdx.x, lane = t & 63;
    const int wavu = __builtin_amdgcn_readfirstlane(t >> 6);
    phase4(smem, x, Bmb, cvec, y, nb1, blockIdx.x, lane, wavu,
           lane & 15, lane >> 4, wavu * 32);
}

extern "C" void kernel_launch(void* const* d_in, const int* in_sizes, int n_in,
                              void* d_out, int out_size, void* d_ws, size_t ws_size,
                              hipStream_t stream)
{
    const float* x     = (const float*)d_in[0];
    const float* w_qkv = (const float*)d_in[1];
    const float* b_qkv = (const float*)d_in[2];
    const float* w_out = (const float*)d_in[3];
    const float* b_out = (const float*)d_in[4];
    float* y = (float*)d_out;

    // ws: ctxP[8][4224] | Bmb[8192 u32] | cvec[128]   (~168 KB)
    char* wsb = (char*)d_ws;
    float* ctxP    = (float*)wsb;
    uint32_t* Bmb  = (uint32_t*)(wsb + (size_t)8 * 4224 * 4);
    float* cvec    = (float*)(wsb + (size_t)8 * 4224 * 4 + (size_t)8192 * 4);

    hipMemsetAsync(ctxP, 0, (size_t)8 * 4224 * sizeof(float), stream);

    // one-time co-residency query (host-side, graph-capture-safe)
    static int coopBlocks = -1;
    if (coopBlocks < 0) {
        int nb = 0;
        hipError_t e = hipOccupancyMaxActiveBlocksPerMultiprocessor(&nb, mono, 256, 0);
        coopBlocks = (e == hipSuccess) ? nb * 256 : 0;   // 256 CUs on MI355X
    }

    int grid = coopBlocks > NB1 ? NB1 : coopBlocks;
    if (grid >= 256) {
        int nb1c = grid;
        void* args[] = { (void*)&x, (void*)&w_qkv, (void*)&b_qkv, (void*)&w_out,
                         (void*)&b_out, (void*)&ctxP, (void*)&Bmb, (void*)&cvec,
                         (void*)&y, (void*)&nb1c };
        hipError_t e = hipLaunchCooperativeKernel((void*)mono, dim3(grid), dim3(256),
                                                  args, 0, stream);
        if (e == hipSuccess) return;
        (void)hipGetLastError();   // clear error, fall through
    }

    // fallback: proven R4 pipeline (same phase code, separate dispatches)
    hipLaunchKernelGGL(k1s, dim3(NB1), dim3(256), 0, stream, x, w_qkv, b_qkv, ctxP, NB1);
    hipLaunchKernelGGL(k2s, dim3(128), dim3(256), 0, stream, ctxP, w_out, w_qkv, b_qkv, b_out, Bmb, cvec);
    hipLaunchKernelGGL(k3s, dim3(NB1), dim3(256), 0, stream, x, Bmb, cvec, y, NB1);
}